// Round 4
// baseline (263.253 us; speedup 1.0000x reference)
//
#include <hip/hip_runtime.h>

// Problem constants
#define LDIM 16384
#define KDIM 288
#define ODIM 64
#define BDIM 8

typedef float f32x4 __attribute__((ext_vector_type(4)));
typedef short bf16x8 __attribute__((ext_vector_type(8)));  // 8 bf16 in 4 VGPRs

// fp32 -> bf16 round-to-nearest-even
__device__ __forceinline__ short f2bf(float f) {
  unsigned u = __builtin_bit_cast(unsigned, f);
  unsigned r = u + 0x7FFFu + ((u >> 16) & 1u);
  return (short)(r >> 16);
}
__device__ __forceinline__ float bf2f(short s) {
  unsigned u = ((unsigned)(unsigned short)s) << 16;
  return __builtin_bit_cast(float, u);
}

// s_waitcnt imm (gfx9): vmcnt[3:0|15:14], expcnt[6:4], lgkmcnt[11:8]
#define WAITCNT_VM4 0x0F74  // vmcnt(4), others unconstrained

// ---------------------------------------------------------------------------
// Pre-kernel, grid=10: blocks 0..8 swizzle W k-chunk kc=blockIdx into MFMA
// B-fragment order, SPLIT bf16 hi/lo; block 9: cw[o] = -gamma * sum_k w2.
// wv[k][o] = w_flat[k*64 + o]  (memory reinterpretation per reference)
// ---------------------------------------------------------------------------
__global__ __launch_bounds__(256) void gauss_pre(const float* __restrict__ w,
                                                 const float* __restrict__ gammap,
                                                 short* __restrict__ wfh,
                                                 short* __restrict__ wfl,
                                                 float* __restrict__ cw) {
  int tid = threadIdx.x;
  int blk = blockIdx.x;

  if (blk < 9) {
    int kc = blk;
    int ln = tid & 63;
    int nt = tid >> 6;
    int k0 = kc * 32 + (ln >> 4) * 8;
    int n = nt * 16 + (ln & 15);
    bf16x8 vh, vl;
#pragma unroll
    for (int j = 0; j < 8; ++j) {
      float v = w[(k0 + j) * 64 + n];
      short h = f2bf(v);
      vh[j] = h;
      vl[j] = f2bf(v - bf2f(h));  // Sterbenz-exact residual, then rounded
    }
    int idx = ((kc * 4 + nt) * 64 + ln) * 8;
    *(bf16x8*)(wfh + idx) = vh;
    *(bf16x8*)(wfl + idx) = vl;
  } else {
    __shared__ float red[256];
    int o = tid & 63;
    int seg = tid >> 6;
    float s = 0.f;
#pragma unroll 8
    for (int k = seg * 72; k < seg * 72 + 72; ++k) {
      float v = w[k * 64 + o];
      s += v * v;
    }
    red[tid] = s;
    __syncthreads();
    if (tid < 64) {
      float t = red[tid] + red[tid + 64] + red[tid + 128] + red[tid + 192];
      cw[tid] = -gammap[0] * t;
    }
  }
}

// ---------------------------------------------------------------------------
// Main kernel v4: BARRIER-FREE. Each wave owns a private triple-buffered
// 4 KB LDS region (its 32 columns x 32 k-rows) staged via global_load_lds;
// the only cross-iteration sync is a per-wave s_waitcnt vmcnt(4) that keeps
// the next STAGE in flight across the whole compute phase (AITER-style).
// Split-precision bf16 (3 MFMA passes) for fp32-accurate xw.
// Block=256 (4 waves), M-tile=128, grid=1024. LDS 48 KB -> 3 blocks/CU.
// ---------------------------------------------------------------------------
__global__ __launch_bounds__(256, 3) void gauss_main(
    const float* __restrict__ x, const short* __restrict__ wfh,
    const short* __restrict__ wfl, const float* __restrict__ cw,
    const float* __restrict__ bias, const float* __restrict__ gammap,
    float* __restrict__ out) {
  __shared__ float abuf[4][3][1024];  // [wave][buf][32 k-rows x 32 cols]

  const int tid = threadIdx.x;
  const int lane = tid & 63;
  const int wvid = tid >> 6;
  const int m = lane & 15;
  const int quad = lane >> 4;

  const long g0 = (long)blockIdx.x * 128;  // global row (b*L + l)
  const int bidx = (int)(g0 >> 14);        // L = 16384
  const int l0 = (int)(g0 & (LDIM - 1));

  // Wave's private 32 columns of x: l = l0 + wvid*32 + [0,32)
  const float* xw = x + (long)bidx * ((long)KDIM * LDIM) + (l0 + wvid * 32);
  // Staging instr i covers k-rows 8i..8i+7: lane ln -> row 8i+(ln>>3),
  // col (ln&7)*4, 16 B each; 128 B contiguous per row, LDS = base+lane*16.
  const int strow = lane >> 3;
  const int stcol = (lane & 7) * 4;

#define STAGE(KC)                                                              \
  {                                                                            \
    const float* xsrc = xw + (long)((KC) * 32 + strow) * LDIM + stcol;         \
    float* lbase = &abuf[wvid][(KC) % 3][0];                                   \
    _Pragma("unroll") for (int i = 0; i < 4; ++i) {                            \
      __builtin_amdgcn_global_load_lds(                                        \
          (const __attribute__((address_space(1))) unsigned int*)(void*)       \
              (xsrc + (long)(8 * i) * LDIM),                                   \
          (__attribute__((address_space(3))) unsigned int*)(lbase + i * 256),  \
          16, 0, 0);                                                           \
    }                                                                          \
  }

  const f32x4 zero = {0.f, 0.f, 0.f, 0.f};
  f32x4 acc[2][4];
#pragma unroll
  for (int t = 0; t < 2; ++t)
#pragma unroll
    for (int nt = 0; nt < 4; ++nt) acc[t][nt] = zero;
  float s2[2] = {0.f, 0.f};

  bf16x8 bh[2][4], bl[2][4];  // ping-pong B fragments (hi/lo)

  // ---- prologue: S(0), B(0), S(1)   (queue order matters for vmcnt math)
  STAGE(0)
  {
    const short* wp = wfh + (0 * 4 * 64 + lane) * 8;
    const short* wq = wfl + (0 * 4 * 64 + lane) * 8;
#pragma unroll
    for (int nt = 0; nt < 4; ++nt) {
      bh[0][nt] = *(const bf16x8*)(wp + nt * 512);
      bl[0][nt] = *(const bf16x8*)(wq + nt * 512);
    }
  }
  STAGE(1)

#pragma unroll
  for (int kc = 0; kc < 9; ++kc) {
    const int cur = kc & 1, nxt = cur ^ 1;

    // Per-wave wait: completes S(kc)+B(kc), leaves S(kc+1) in flight.
    __builtin_amdgcn_s_waitcnt(WAITCNT_VM4);

    // A fragments from own LDS region (4-way bank alias, ~free per m136)
    const float* ab = &abuf[wvid][kc % 3][0];
    float a[2][8];
#pragma unroll
    for (int t = 0; t < 2; ++t)
#pragma unroll
      for (int j = 0; j < 8; ++j) a[t][j] = ab[(quad * 8 + j) * 32 + t * 16 + m];

    // Prefetch B(kc+1), then issue S(kc+2): both ride through next wait.
    if (kc < 8) {
      const short* wp = wfh + ((kc + 1) * 4 * 64 + lane) * 8;
      const short* wq = wfl + ((kc + 1) * 4 * 64 + lane) * 8;
#pragma unroll
      for (int nt = 0; nt < 4; ++nt) {
        bh[nxt][nt] = *(const bf16x8*)(wp + nt * 512);
        bl[nxt][nt] = *(const bf16x8*)(wq + nt * 512);
      }
    }
    if (kc < 7) STAGE(kc + 2)

    // Convert (split hi/lo) + |x|^2 + 3-pass MFMA
#pragma unroll
    for (int t = 0; t < 2; ++t) {
      bf16x8 ah, al;
#pragma unroll
      for (int j = 0; j < 8; ++j) {
        float v = a[t][j];
        s2[t] += v * v;
        short h = f2bf(v);
        ah[j] = h;
        al[j] = f2bf(v - bf2f(h));
      }
#pragma unroll
      for (int nt = 0; nt < 4; ++nt) {
        acc[t][nt] = __builtin_amdgcn_mfma_f32_16x16x32_bf16(ah, bh[cur][nt],
                                                             acc[t][nt], 0, 0, 0);
        acc[t][nt] = __builtin_amdgcn_mfma_f32_16x16x32_bf16(al, bh[cur][nt],
                                                             acc[t][nt], 0, 0, 0);
        acc[t][nt] = __builtin_amdgcn_mfma_f32_16x16x32_bf16(ah, bl[cur][nt],
                                                             acc[t][nt], 0, 0, 0);
      }
    }
  }

  // ---- finish |x|^2 across quads
#pragma unroll
  for (int t = 0; t < 2; ++t) {
    s2[t] += __shfl_xor(s2[t], 16, 64);
    s2[t] += __shfl_xor(s2[t], 32, 64);
  }

  const float gamma = gammap[0];
  float cwv[4], bv[4];
#pragma unroll
  for (int nt = 0; nt < 4; ++nt) {
    int col = nt * 16 + m;
    cwv[nt] = cw[col];
    bv[nt] = bias[col];
  }

  // ---- epilogue: C-layout -> wave-private LDS -> 1 KB contiguous stores.
  // No barrier needed: region is private; compiler orders intra-wave LDS.
  float* ob = &abuf[wvid][0][0];  // 2048 of 3072 floats used
  const float coef = 2.f * gamma;
#pragma unroll
  for (int t = 0; t < 2; ++t) {
#pragma unroll
    for (int r = 0; r < 4; ++r) {
      int row = quad * 4 + r;
      float x2v = __shfl(s2[t], (lane & 48) | row, 64);
      float cx = -gamma * x2v;
      int lr = t * 16 + row;
#pragma unroll
      for (int nt = 0; nt < 4; ++nt) {
        float e = __builtin_fmaf(coef, acc[t][nt][r], cx + cwv[nt]);
        ob[lr * 64 + nt * 16 + m] = __expf(e) + bv[nt];
      }
    }
  }

  float* outw = out + (g0 + wvid * 32) * 64;
#pragma unroll
  for (int j = 0; j < 8; ++j) {
    f32x4 v = *(f32x4*)&ob[j * 256 + lane * 4];
    *(f32x4*)(outw + (j * 4 + (lane >> 4)) * 64 + (lane & 15) * 4) = v;
  }
}

extern "C" void kernel_launch(void* const* d_in, const int* in_sizes, int n_in,
                              void* d_out, int out_size, void* d_ws, size_t ws_size,
                              hipStream_t stream) {
  const float* x = (const float*)d_in[0];      // [8, 288, 16384]
  const float* w = (const float*)d_in[1];      // [64, 32, 3, 3] -> flat 18432
  const float* b = (const float*)d_in[2];      // [64]
  const float* gamma = (const float*)d_in[3];  // scalar
  float* out = (float*)d_out;                  // [8, 16384, 64]

  short* wfh = (short*)d_ws;                   // 36864 B
  short* wfl = (short*)((char*)d_ws + 36864);  // 36864 B
  float* cw = (float*)((char*)d_ws + 73728);   // 64 floats

  gauss_pre<<<10, 256, 0, stream>>>(w, gamma, wfh, wfl, cw);
  gauss_main<<<1024, 256, 0, stream>>>(x, wfh, wfl, cw, b, gamma, out);
}

// Round 5
// 255.191 us; speedup vs baseline: 1.0316x; 1.0316x over previous
//
#include <hip/hip_runtime.h>

// Problem constants
#define LDIM 16384
#define KDIM 288
#define ODIM 64
#define BDIM 8

typedef float f32x4 __attribute__((ext_vector_type(4)));
typedef _Float16 f16x8 __attribute__((ext_vector_type(8)));  // 8 f16 in 4 VGPRs

// ---------------------------------------------------------------------------
// Pre-kernel, grid=10: blocks 0..8 swizzle W k-chunk kc=blockIdx into MFMA
// B-fragment order (fp16, RNE); block 9: cw[o] = -gamma * sum_k w[k][o]^2.
// wv[k][o] = w_flat[k*64 + o]  (memory reinterpretation per reference)
// ---------------------------------------------------------------------------
__global__ __launch_bounds__(256) void gauss_pre(const float* __restrict__ w,
                                                 const float* __restrict__ gammap,
                                                 _Float16* __restrict__ wf,
                                                 float* __restrict__ cw) {
  int tid = threadIdx.x;
  int blk = blockIdx.x;

  if (blk < 9) {
    int kc = blk;
    int ln = tid & 63;
    int nt = tid >> 6;
    int k0 = kc * 32 + (ln >> 4) * 8;
    int n = nt * 16 + (ln & 15);
    f16x8 v;
#pragma unroll
    for (int j = 0; j < 8; ++j) v[j] = (_Float16)w[(k0 + j) * 64 + n];
    *(f16x8*)(wf + ((kc * 4 + nt) * 64 + ln) * 8) = v;
  } else {
    __shared__ float red[256];
    int o = tid & 63;
    int seg = tid >> 6;
    float s = 0.f;
#pragma unroll 8
    for (int k = seg * 72; k < seg * 72 + 72; ++k) {
      float v = w[k * 64 + o];
      s += v * v;
    }
    red[tid] = s;
    __syncthreads();
    if (tid < 64) {
      float t = red[tid] + red[tid + 64] + red[tid + 128] + red[tid + 192];
      cw[tid] = -gammap[0] * t;
    }
  }
}

// ---------------------------------------------------------------------------
// Main kernel v5: WIDE L-tile for DRAM efficiency. M-tile = 256 l-cols
// (every staged row is a 1 KB contiguous chunk -> ~full DRAM page efficiency,
// vs 512 B / ~50% in rounds 1-3). K-chunk = 32, double-buffered 2x32 KB LDS
// staged via global_load_lds (width 16), one barrier per iteration (per-CU
// supply time ~6.4k cyc >> 900-cyc latency, so the barrier drain is hidden
// behind supply). Single-pass fp16 MFMA (no split => no spills).
// Block = 256 (4 waves, each owning 64 l-cols x all 64 o-cols, 64 AGPR acc).
// Grid = B*L/256 = 512 blocks -> exactly 2 blocks/CU (LDS-limited).
// ---------------------------------------------------------------------------
__global__ __launch_bounds__(256, 2) void gauss_main(
    const float* __restrict__ x, const _Float16* __restrict__ wf,
    const float* __restrict__ cw, const float* __restrict__ bias,
    const float* __restrict__ gammap, float* __restrict__ out) {
  __shared__ float abuf[2][32 * 256];  // 2 x 32 KB

  const int tid = threadIdx.x;
  const int lane = tid & 63;
  const int wvid = tid >> 6;
  const int m = lane & 15;
  const int quad = lane >> 4;

  const long g0 = (long)blockIdx.x * 256;  // global row (b*L + l)
  const int bidx = (int)(g0 >> 14);        // L = 16384
  const int l0 = (int)(g0 & (LDIM - 1));

  const float* xb = x + (long)bidx * ((long)KDIM * LDIM) + l0;

  // Staging: wave wvid stages k-rows wvid*8 .. wvid*8+7 of the chunk; each
  // instruction moves one full 256-col row: lane's 16 B at col lane*4.
  // LDS dest is wave-uniform base + lane*16 (global_load_lds requirement).
#define STAGE(KC, BUF)                                                         \
  {                                                                            \
    const float* xsrc = xb + (long)((KC) * 32 + wvid * 8) * LDIM + lane * 4;   \
    float* lb = &abuf[BUF][(wvid * 8) * 256];                                  \
    _Pragma("unroll") for (int i = 0; i < 8; ++i) {                            \
      __builtin_amdgcn_global_load_lds(                                        \
          (const __attribute__((address_space(1))) unsigned int*)(void*)       \
              (xsrc + (long)i * LDIM),                                         \
          (__attribute__((address_space(3))) unsigned int*)(lb + i * 256),     \
          16, 0, 0);                                                           \
    }                                                                          \
  }

  const f32x4 zero = {0.f, 0.f, 0.f, 0.f};
  f32x4 acc[4][4];  // [t: m-tile][nt: n-tile] -> 64 AGPRs
#pragma unroll
  for (int t = 0; t < 4; ++t)
#pragma unroll
    for (int nt = 0; nt < 4; ++nt) acc[t][nt] = zero;
  float s2[4] = {0.f, 0.f, 0.f, 0.f};

  f16x8 bf[2][4];  // ping-pong B fragments

  // ---- prologue: stage chunk 0, load B(0)
  STAGE(0, 0)
  {
    const _Float16* wp = wf + (0 * 4 * 64 + lane) * 8;
#pragma unroll
    for (int nt = 0; nt < 4; ++nt) bf[0][nt] = *(const f16x8*)(wp + nt * 512);
  }
  __syncthreads();  // drains S(0)

#pragma unroll
  for (int kc = 0; kc < 9; ++kc) {
    const int pb = kc & 1;

    // prefetch next chunk + next B while computing this one
    if (kc < 8) {
      STAGE(kc + 1, pb ^ 1)
      const _Float16* wp = wf + ((kc + 1) * 4 * 64 + lane) * 8;
#pragma unroll
      for (int nt = 0; nt < 4; ++nt)
        bf[pb ^ 1][nt] = *(const f16x8*)(wp + nt * 512);
    }

    // compute: 4 m-tiles x 4 n-tiles, K=32
#pragma unroll
    for (int t = 0; t < 4; ++t) {
      const float* ap = &abuf[pb][(quad * 8) * 256 + wvid * 64 + t * 16 + m];
      float a[8];
#pragma unroll
      for (int j = 0; j < 8; ++j) a[j] = ap[j * 256];
      f16x8 af;
#pragma unroll
      for (int j = 0; j < 8; ++j) {
        s2[t] += a[j] * a[j];
        af[j] = (_Float16)a[j];
      }
#pragma unroll
      for (int nt = 0; nt < 4; ++nt)
        acc[t][nt] =
            __builtin_amdgcn_mfma_f32_16x16x32_f16(af, bf[pb][nt], acc[t][nt], 0, 0, 0);
    }

    if (kc < 8) __syncthreads();  // waves done with buf pb; S(kc+1) drained
  }

  // ---- finish |x|^2 across quads (each lane then holds full sum for its m)
#pragma unroll
  for (int t = 0; t < 4; ++t) {
    s2[t] += __shfl_xor(s2[t], 16, 64);
    s2[t] += __shfl_xor(s2[t], 32, 64);
  }

  const float gamma = gammap[0];
  float cwv[4], bv[4];
#pragma unroll
  for (int nt = 0; nt < 4; ++nt) {
    int col = nt * 16 + m;
    cwv[nt] = cw[col];
    bv[nt] = bias[col];
  }

  __syncthreads();  // staging buffers retired by ALL waves before epilogue reuse

  // ---- epilogue: C-layout -> LDS transpose -> contiguous 1 KB stores.
  // Wave-private 16 KB region; wave's out block is 4096 contiguous floats.
  float* ob = &abuf[0][0] + wvid * 4096;
  const float coef = 2.f * gamma;
#pragma unroll
  for (int t = 0; t < 4; ++t) {
#pragma unroll
    for (int r = 0; r < 4; ++r) {
      int row = quad * 4 + r;  // C/D: row = quad*4 + reg, col = lane&15
      float x2v = __shfl(s2[t], (lane & 48) | row, 64);
      float cx = -gamma * x2v;
      int lr = t * 16 + row;  // l-local within wave's 64 rows
#pragma unroll
      for (int nt = 0; nt < 4; ++nt) {
        float e = __builtin_fmaf(coef, acc[t][nt][r], cx + cwv[nt]);
        ob[lr * 64 + nt * 16 + m] = __expf(e) + bv[nt];
      }
    }
  }

  float* outw = out + (g0 + wvid * 64) * 64;  // 4096 contiguous floats
#pragma unroll
  for (int j = 0; j < 16; ++j) {
    f32x4 v = *(f32x4*)&ob[j * 256 + lane * 4];
    *(f32x4*)(outw + j * 256 + lane * 4) = v;
  }
}

extern "C" void kernel_launch(void* const* d_in, const int* in_sizes, int n_in,
                              void* d_out, int out_size, void* d_ws, size_t ws_size,
                              hipStream_t stream) {
  const float* x = (const float*)d_in[0];      // [8, 288, 16384]
  const float* w = (const float*)d_in[1];      // [64, 32, 3, 3] -> flat 18432
  const float* b = (const float*)d_in[2];      // [64]
  const float* gamma = (const float*)d_in[3];  // scalar
  float* out = (float*)d_out;                  // [8, 16384, 64]

  _Float16* wf = (_Float16*)d_ws;             // 36864 B fp16 B-fragments
  float* cw = (float*)((char*)d_ws + 36864);  // 64 floats

  gauss_pre<<<10, 256, 0, stream>>>(w, gamma, wf, cw);
  gauss_main<<<512, 256, 0, stream>>>(x, wf, cw, b, gamma, out);
}